// Round 2
// baseline (538.819 us; speedup 1.0000x reference)
//
#include <hip/hip_runtime.h>
#include <hip/hip_bf16.h>
#include <cstdint>

// LocalAttention fused kernel, round 2: f32 I/O (per reference dtypes),
// fp32 accumulate, gated neighbors cached in LDS as bf16.
//
// Algebraic restructure (exact in real arithmetic):
//   energy[h,n] = sum_j an[n,j] * t[h,j],  t[h,j] = 0.25 * sum_d' q[h,d'] Wk[j, h*16+d']
//     (bk adds a per-(c,h) constant over n -> cancels in softmax; bk==0 anyway)
//   ctx[h,d']  = sum_j s[h,j] * Wv[j, h*16+d'] + (sum_n attnm[h,n]) * bv[h,d']
//     with s[h,:] = attnm[h,:] @ an,  attnm = attn * mask
// Cuts FLOPs ~8x vs materializing k,v; kernel streams atom_neighbor (256 MB f32).
//
// Block: G_=4 c-columns of one b; 256 threads; LDS 66.3 KB -> 2 blocks/CU.

#define B_ 16
#define C_ 1024
#define N_ 32
#define H_ 8
#define D_ 128
#define G_ 4
#define T_ 256

typedef unsigned short u16;
typedef unsigned int u32;

__device__ __forceinline__ float bflo(u32 u) {
    union { u32 i; float f; } v; v.i = u << 16; return v.f;
}
__device__ __forceinline__ float bfhi(u32 u) {
    union { u32 i; float f; } v; v.i = u & 0xffff0000u; return v.f;
}
__device__ __forceinline__ u16 f2bf(float f) {
    union { float f; u32 i; } v; v.f = f;
    u32 x = v.i;
    u32 r = (x + 0x7fffu + ((x >> 16) & 1u)) >> 16;
    return (u16)r;
}
__device__ __forceinline__ u32 pack2(float a, float b) {
    return (u32)f2bf(a) | ((u32)f2bf(b) << 16);
}
__device__ __forceinline__ float swishf(float x) {
    float s = __builtin_amdgcn_rcpf(1.0f + __expf(-x));
    return x * s;
}

__global__ __launch_bounds__(T_, 2)
void la_kernel(const float* __restrict__ aq_g,  const float* __restrict__ an_g,
               const float* __restrict__ dist_g, const float* __restrict__ mask_g,
               const float* __restrict__ wq_g,  const float* __restrict__ bq_g,
               const float* __restrict__ wk_g,
               const float* __restrict__ wv_g,  const float* __restrict__ bv_g,
               const float* __restrict__ wf_g,  const float* __restrict__ bfb_g,
               float* __restrict__ attn_o, float* __restrict__ ctx_o)
{
    // LDS: 34816 + 16896 + 2048 + 2048 + 4224 + 4096 + 512 + 512 + 128 + 1024 = 66304 B
    __shared__ __align__(16) u16   s_an[G_ * N_ * 136];   // gated neighbors, bf16, row pad 128->136
    __shared__ __align__(16) float s_ts[G_ * H_ * 132];   // t (phase C/D), then s (phase F/G)
    __shared__ float s_q[G_][D_];                         // projected query (unscaled)
    __shared__ float s_aq[G_][D_];                        // raw atom_query
    __shared__ float s_eat[G_][H_][33];                   // energy (D/E), then attnm (F)
    __shared__ float s_ao[G_][H_][N_];                    // attn (pre-mask) for output
    __shared__ float s_dist[G_][N_];
    __shared__ float s_mask[G_][N_];
    __shared__ float s_asum[G_][H_];
    __shared__ __align__(16) float s_wf[D_];
    __shared__ __align__(16) float s_bfb[D_];

    const int tid = threadIdx.x;
    const int b   = blockIdx.x >> 8;          // 256 c-groups per b
    const int c0  = (blockIdx.x & 255) << 2;  // G_=4 c's per block

    // ---- Phase 0: stage small tensors ----
    if (tid < D_) {
        s_wf[tid]  = wf_g[tid];
        s_bfb[tid] = bfb_g[tid];
        int c = tid >> 5, n = tid & 31;
        int gi = (b * C_ + c0 + c) * N_ + n;
        s_dist[c][n] = dist_g[gi];
        s_mask[c][n] = mask_g[gi];
    }
    {
        int c = tid >> 7, d = tid & 127;
        s_aq[c][d] = aq_g[(b * C_ + c0 + c) * D_ + d];
        int i2 = tid + 256;
        c = i2 >> 7; d = i2 & 127;
        s_aq[c][d] = aq_g[(b * C_ + c0 + c) * D_ + d];
    }
    __syncthreads();

    // ---- Phase A: stream + swish-gate atom_neighbor -> s_an (bf16) ----
    {
        const float4* gan = (const float4*)(an_g + (size_t)(b * C_ + c0) * N_ * D_);
        #pragma unroll
        for (int k = 0; k < 16; k++) {
            int ci = k * T_ + tid;                  // float4 chunk index, 4096 total
            float4 v = gan[ci];
            int d4 = ci & 31, n = (ci >> 5) & 31, c = ci >> 10;
            float dist = s_dist[c][n];
            int d0 = d4 << 2;
            float4 wf = *(const float4*)&s_wf[d0];
            float4 bb = *(const float4*)&s_bfb[d0];
            float g0 = swishf(fmaf(dist, wf.x, bb.x));
            float g1 = swishf(fmaf(dist, wf.y, bb.y));
            float g2 = swishf(fmaf(dist, wf.z, bb.z));
            float g3 = swishf(fmaf(dist, wf.w, bb.w));
            u32 o0 = pack2(v.x * g0, v.y * g1);
            u32 o1 = pack2(v.z * g2, v.w * g3);
            *(uint2*)(s_an + (c * N_ + n) * 136 + d0) = make_uint2(o0, o1);
        }
    }

    // ---- Phase B: q_proj[c, od] = atom_query @ Wq + bq ----
    {
        int op = tid & 63, c = tid >> 6;   // wave == c; lanes sweep output pairs
        int od = op << 1;
        float acc0 = 0.f, acc1 = 0.f;
        #pragma unroll 8
        for (int j = 0; j < D_; j++) {
            float2 w = ((const float2*)(wq_g + j * D_))[op];
            float a = s_aq[c][j];
            acc0 = fmaf(a, w.x, acc0);
            acc1 = fmaf(a, w.y, acc1);
        }
        s_q[c][od]     = acc0 + bq_g[od];
        s_q[c][od + 1] = acc1 + bq_g[od + 1];
    }
    __syncthreads();

    // ---- Phase C: t[c,h,j] = 0.25 * sum_d' q[c,h*16+d'] * Wk[j, h*16+d'] ----
    {
        int h = tid & 7, jb = tid >> 3;    // jb in 0..31, j = jb + jj*32
        float wk[4][16];
        #pragma unroll
        for (int jj = 0; jj < 4; jj++) {
            int j = jb + jj * 32;
            const float4* pk = (const float4*)(wk_g + j * D_ + h * 16);
            float4 k0 = pk[0], k1 = pk[1], k2 = pk[2], k3 = pk[3];
            wk[jj][0]  = k0.x; wk[jj][1]  = k0.y; wk[jj][2]  = k0.z; wk[jj][3]  = k0.w;
            wk[jj][4]  = k1.x; wk[jj][5]  = k1.y; wk[jj][6]  = k1.z; wk[jj][7]  = k1.w;
            wk[jj][8]  = k2.x; wk[jj][9]  = k2.y; wk[jj][10] = k2.z; wk[jj][11] = k2.w;
            wk[jj][12] = k3.x; wk[jj][13] = k3.y; wk[jj][14] = k3.z; wk[jj][15] = k3.w;
        }
        #pragma unroll
        for (int c = 0; c < G_; c++) {
            float qv[16];
            #pragma unroll
            for (int d = 0; d < 16; d++) qv[d] = s_q[c][h * 16 + d];
            #pragma unroll
            for (int jj = 0; jj < 4; jj++) {
                float acc = 0.f;
                #pragma unroll
                for (int d = 0; d < 16; d++) acc = fmaf(qv[d], wk[jj][d], acc);
                s_ts[(c * H_ + h) * 132 + jb + jj * 32] = acc * 0.25f;
            }
        }
    }
    __syncthreads();

    // ---- Phase D: energy[c,h,n] = sum_j an[c,n,j] * t[c,h,j], + mask bias ----
    {
        int c = tid >> 6, h = (tid >> 3) & 7, n0 = tid & 7;
        const float* trow = &s_ts[(c * H_ + h) * 132];
        float acc[4] = {0.f, 0.f, 0.f, 0.f};
        #pragma unroll
        for (int jc = 0; jc < 16; jc++) {
            float4 ta = *(const float4*)(trow + jc * 8);
            float4 tb = *(const float4*)(trow + jc * 8 + 4);
            #pragma unroll
            for (int r = 0; r < 4; r++) {
                int n = n0 + r * 8;
                uint4 av = *(const uint4*)(s_an + (c * N_ + n) * 136 + jc * 8);
                float s = acc[r];
                s = fmaf(bflo(av.x), ta.x, s);  s = fmaf(bfhi(av.x), ta.y, s);
                s = fmaf(bflo(av.y), ta.z, s);  s = fmaf(bfhi(av.y), ta.w, s);
                s = fmaf(bflo(av.z), tb.x, s);  s = fmaf(bfhi(av.z), tb.y, s);
                s = fmaf(bflo(av.w), tb.z, s);  s = fmaf(bfhi(av.w), tb.w, s);
                acc[r] = s;
            }
        }
        #pragma unroll
        for (int r = 0; r < 4; r++) {
            int n = n0 + r * 8;
            float mk = s_mask[c][n];
            s_eat[c][h][n] = acc[r] + (1.0f - mk) * (-1.0e9f);
        }
    }
    __syncthreads();

    // ---- Phase E: softmax over n per (c,h); attn, attnm, asum ----
    if (tid < G_ * H_) {
        int c = tid >> 3, h = tid & 7;
        float e[N_];
        float m = -3.0e38f;
        #pragma unroll
        for (int n = 0; n < N_; n++) { e[n] = s_eat[c][h][n]; m = fmaxf(m, e[n]); }
        float sum = 0.f;
        #pragma unroll
        for (int n = 0; n < N_; n++) { float p = __expf(e[n] - m); e[n] = p; sum += p; }
        float inv = 1.0f / sum;
        float asum = 0.f;
        #pragma unroll
        for (int n = 0; n < N_; n++) {
            float a  = e[n] * inv;
            float am = a * s_mask[c][n];
            s_ao[c][h][n]  = a;
            s_eat[c][h][n] = am;
            asum += am;
        }
        s_asum[c][h] = asum;
    }
    __syncthreads();

    // ---- Phase E2: write attn output (f32, [B,H,C,N]) ----
    {
        int ch = tid >> 3, i8 = tid & 7;
        int c = ch >> 3, h = ch & 7;
        float4 w;
        w.x = s_ao[c][h][i8 * 4];
        w.y = s_ao[c][h][i8 * 4 + 1];
        w.z = s_ao[c][h][i8 * 4 + 2];
        w.w = s_ao[c][h][i8 * 4 + 3];
        size_t off = ((size_t)(b * H_ + h) * C_ + (c0 + c)) * N_ + i8 * 4;
        *(float4*)(attn_o + off) = w;
    }

    // ---- Phase F: s[c,h,j] = sum_n attnm[c,h,n] * an[c,n,j] (overwrites s_ts) ----
    {
        int c = tid >> 6, h = (tid >> 3) & 7, jg = tid & 7;
        int j0 = jg * 16;
        float acc[16];
        #pragma unroll
        for (int i = 0; i < 16; i++) acc[i] = 0.f;
        #pragma unroll 4
        for (int n = 0; n < N_; n++) {
            float am = s_eat[c][h][n];
            const u16* arow = s_an + (c * N_ + n) * 136 + j0;
            uint4 v0 = *(const uint4*)(arow);
            uint4 v1 = *(const uint4*)(arow + 8);
            acc[0]  = fmaf(am, bflo(v0.x), acc[0]);   acc[1]  = fmaf(am, bfhi(v0.x), acc[1]);
            acc[2]  = fmaf(am, bflo(v0.y), acc[2]);   acc[3]  = fmaf(am, bfhi(v0.y), acc[3]);
            acc[4]  = fmaf(am, bflo(v0.z), acc[4]);   acc[5]  = fmaf(am, bfhi(v0.z), acc[5]);
            acc[6]  = fmaf(am, bflo(v0.w), acc[6]);   acc[7]  = fmaf(am, bfhi(v0.w), acc[7]);
            acc[8]  = fmaf(am, bflo(v1.x), acc[8]);   acc[9]  = fmaf(am, bfhi(v1.x), acc[9]);
            acc[10] = fmaf(am, bflo(v1.y), acc[10]);  acc[11] = fmaf(am, bfhi(v1.y), acc[11]);
            acc[12] = fmaf(am, bflo(v1.z), acc[12]);  acc[13] = fmaf(am, bfhi(v1.z), acc[13]);
            acc[14] = fmaf(am, bflo(v1.w), acc[14]);  acc[15] = fmaf(am, bfhi(v1.w), acc[15]);
        }
        float* srow = &s_ts[(c * H_ + h) * 132 + j0];
        *(float4*)(srow)      = make_float4(acc[0], acc[1], acc[2], acc[3]);
        *(float4*)(srow + 4)  = make_float4(acc[4], acc[5], acc[6], acc[7]);
        *(float4*)(srow + 8)  = make_float4(acc[8], acc[9], acc[10], acc[11]);
        *(float4*)(srow + 12) = make_float4(acc[12], acc[13], acc[14], acc[15]);
    }
    __syncthreads();

    // ---- Phase G: context[c, od] = s[c,h,:] @ Wv[:, od] + asum*bv + q_proj ----
    {
        int op = tid & 63, c = tid >> 6;
        int od = op << 1;
        int h  = od >> 4;
        const float* srow = &s_ts[(c * H_ + h) * 132];
        float acc0 = 0.f, acc1 = 0.f;
        #pragma unroll 8
        for (int j = 0; j < D_; j++) {
            float2 w = ((const float2*)(wv_g + j * D_))[op];
            float sv = srow[j];
            acc0 = fmaf(sv, w.x, acc0);
            acc1 = fmaf(sv, w.y, acc1);
        }
        float as = s_asum[c][h];
        float2 r;
        r.x = acc0 + as * bv_g[od]     + s_q[c][od];
        r.y = acc1 + as * bv_g[od + 1] + s_q[c][od + 1];
        size_t off = ((size_t)(b * C_ + c0 + c)) * D_ + od;
        *(float2*)(ctx_o + off) = r;
    }
}

extern "C" void kernel_launch(void* const* d_in, const int* in_sizes, int n_in,
                              void* d_out, int out_size, void* d_ws, size_t ws_size,
                              hipStream_t stream) {
    const float* aq   = (const float*)d_in[0];
    const float* an   = (const float*)d_in[1];
    const float* dist = (const float*)d_in[2];
    const float* mask = (const float*)d_in[3];
    const float* wq   = (const float*)d_in[4];
    const float* bq   = (const float*)d_in[5];
    const float* wk   = (const float*)d_in[6];
    // d_in[7] = bk: adds a per-(c,h) constant over n -> cancels exactly in softmax.
    const float* wv   = (const float*)d_in[8];
    const float* bv   = (const float*)d_in[9];
    const float* wf   = (const float*)d_in[10];
    const float* bfb  = (const float*)d_in[11];

    float* attn_o = (float*)d_out;
    float* ctx_o  = attn_o + (size_t)B_ * H_ * C_ * N_;

    dim3 grid(B_ * C_ / G_), block(T_);
    hipLaunchKernelGGL(la_kernel, grid, block, 0, stream,
                       aq, an, dist, mask, wq, bq, wk, wv, bv, wf, bfb,
                       attn_o, ctx_o);
}

// Round 3
// 461.944 us; speedup vs baseline: 1.1664x; 1.1664x over previous
//
#include <hip/hip_runtime.h>
#include <hip/hip_bf16.h>
#include <cstdint>

// LocalAttention fused kernel, round 3: f32 I/O, fp32 accumulate, gated
// neighbors cached in LDS as bf16. vs round 2: cooperative weight loading
// (Wq/Wv read once per block, 4x less L2 traffic) + register prefetch of
// weight slices to overlap the an-stream / attention phases (latency fix
// for the 36%-VALUBusy latency-bound profile).
//
// Algebraic restructure (exact in real arithmetic):
//   energy[h,n] = sum_j an[n,j] * t[h,j],  t[h,j] = 0.25 * sum_d' q[h,d'] Wk[j, h*16+d']
//     (bk adds a per-(c,h) constant over n -> cancels in softmax; bk==0 anyway)
//   ctx[h,d']  = sum_j s[h,j] * Wv[j, h*16+d'] + (sum_n attnm[h,n]) * bv[h,d']
//     with s[h,:] = attnm[h,:] @ an,  attnm = attn * mask
//
// Block: G_=4 c-columns of one b; 256 threads; LDS 66.3 KB -> 2 blocks/CU.

#define B_ 16
#define C_ 1024
#define N_ 32
#define H_ 8
#define D_ 128
#define G_ 4
#define T_ 256

typedef unsigned short u16;
typedef unsigned int u32;

__device__ __forceinline__ float bflo(u32 u) {
    union { u32 i; float f; } v; v.i = u << 16; return v.f;
}
__device__ __forceinline__ float bfhi(u32 u) {
    union { u32 i; float f; } v; v.i = u & 0xffff0000u; return v.f;
}
__device__ __forceinline__ u16 f2bf(float f) {
    union { float f; u32 i; } v; v.f = f;
    u32 x = v.i;
    u32 r = (x + 0x7fffu + ((x >> 16) & 1u)) >> 16;
    return (u16)r;
}
__device__ __forceinline__ u32 pack2(float a, float b) {
    return (u32)f2bf(a) | ((u32)f2bf(b) << 16);
}
__device__ __forceinline__ float swishf(float x) {
    float s = __builtin_amdgcn_rcpf(1.0f + __expf(-x));
    return x * s;
}

__global__ __launch_bounds__(T_, 2)
void la_kernel(const float* __restrict__ aq_g,  const float* __restrict__ an_g,
               const float* __restrict__ dist_g, const float* __restrict__ mask_g,
               const float* __restrict__ wq_g,  const float* __restrict__ bq_g,
               const float* __restrict__ wk_g,
               const float* __restrict__ wv_g,  const float* __restrict__ bv_g,
               const float* __restrict__ wf_g,  const float* __restrict__ bfb_g,
               float* __restrict__ attn_o, float* __restrict__ ctx_o)
{
    // LDS: same 66304 B as round 2 (scratch regions are reused, not added).
    __shared__ __align__(16) u16   s_an[G_ * N_ * 136];   // gated neighbors bf16; float scratch for G-partials after F
    __shared__ __align__(16) float s_ts[G_ * H_ * 132];   // B-partials, then t (C/D), then s (F/G)
    __shared__ float s_q[G_][D_];                         // projected query (unscaled)
    __shared__ float s_aq[G_][D_];                        // raw atom_query
    __shared__ float s_eat[G_][H_][33];                   // energy (D/E), then attnm (F)
    __shared__ float s_ao[G_][H_][N_];                    // attn (pre-mask) for output
    __shared__ float s_dist[G_][N_];
    __shared__ float s_mask[G_][N_];
    __shared__ float s_asum[G_][H_];
    __shared__ __align__(16) float s_wf[D_];
    __shared__ __align__(16) float s_bfb[D_];

    const int tid = threadIdx.x;
    const int b   = blockIdx.x >> 8;          // 256 c-groups per b
    const int c0  = (blockIdx.x & 255) << 2;  // G_=4 c's per block

    const int op = tid & 63;                  // output-pair index (od = 2*op)
    const int js = tid >> 6;                  // j-slice index (rows js*32 .. js*32+31)

    // ---- Prefetch Wq slice into registers (overlaps Phase A an-stream) ----
    float2 wq2[32];
    #pragma unroll
    for (int i = 0; i < 32; i++)
        wq2[i] = ((const float2*)(wq_g + (size_t)(js * 32 + i) * D_))[op];

    // ---- Phase 0: stage small tensors ----
    if (tid < D_) {
        s_wf[tid]  = wf_g[tid];
        s_bfb[tid] = bfb_g[tid];
        int c = tid >> 5, n = tid & 31;
        int gi = (b * C_ + c0 + c) * N_ + n;
        s_dist[c][n] = dist_g[gi];
        s_mask[c][n] = mask_g[gi];
    }
    {
        int c = tid >> 7, d = tid & 127;
        s_aq[c][d] = aq_g[(b * C_ + c0 + c) * D_ + d];
        int i2 = tid + 256;
        c = i2 >> 7; d = i2 & 127;
        s_aq[c][d] = aq_g[(b * C_ + c0 + c) * D_ + d];
    }
    __syncthreads();

    // ---- Phase A: stream + swish-gate atom_neighbor -> s_an (bf16) ----
    {
        const float4* gan = (const float4*)(an_g + (size_t)(b * C_ + c0) * N_ * D_);
        #pragma unroll
        for (int k = 0; k < 16; k++) {
            int ci = k * T_ + tid;                  // float4 chunk index, 4096 total
            float4 v = gan[ci];
            int d4 = ci & 31, n = (ci >> 5) & 31, c = ci >> 10;
            float dist = s_dist[c][n];
            int d0 = d4 << 2;
            float4 wf = *(const float4*)&s_wf[d0];
            float4 bb = *(const float4*)&s_bfb[d0];
            float g0 = swishf(fmaf(dist, wf.x, bb.x));
            float g1 = swishf(fmaf(dist, wf.y, bb.y));
            float g2 = swishf(fmaf(dist, wf.z, bb.z));
            float g3 = swishf(fmaf(dist, wf.w, bb.w));
            u32 o0 = pack2(v.x * g0, v.y * g1);
            u32 o1 = pack2(v.z * g2, v.w * g3);
            *(uint2*)(s_an + (c * N_ + n) * 136 + d0) = make_uint2(o0, o1);
        }
    }

    // ---- Phase B: q partials — thread (op,js) covers j in [js*32, js*32+32) ----
    // Wq is read ONCE per block (64 KB) instead of once per wave (256 KB).
    {
        float acc0[G_], acc1[G_];
        #pragma unroll
        for (int c = 0; c < G_; c++) { acc0[c] = 0.f; acc1[c] = 0.f; }
        #pragma unroll
        for (int i4 = 0; i4 < 8; i4++) {
            #pragma unroll
            for (int c = 0; c < G_; c++) {
                float4 a4 = *(const float4*)&s_aq[c][js * 32 + i4 * 4];
                float2 w0 = wq2[i4 * 4], w1 = wq2[i4 * 4 + 1];
                float2 w2 = wq2[i4 * 4 + 2], w3 = wq2[i4 * 4 + 3];
                acc0[c] = fmaf(a4.x, w0.x, acc0[c]); acc1[c] = fmaf(a4.x, w0.y, acc1[c]);
                acc0[c] = fmaf(a4.y, w1.x, acc0[c]); acc1[c] = fmaf(a4.y, w1.y, acc1[c]);
                acc0[c] = fmaf(a4.z, w2.x, acc0[c]); acc1[c] = fmaf(a4.z, w2.y, acc1[c]);
                acc0[c] = fmaf(a4.w, w3.x, acc0[c]); acc1[c] = fmaf(a4.w, w3.y, acc1[c]);
            }
        }
        float* s_part = s_ts;   // [js][c][128] scratch, 8 KB
        #pragma unroll
        for (int c = 0; c < G_; c++) {
            *(float2*)&s_part[(js * G_ + c) * D_ + 2 * op] = make_float2(acc0[c], acc1[c]);
        }
    }
    __syncthreads();

    // ---- Phase B2: reduce partials -> s_q ----
    {
        const float* s_part = s_ts;
        #pragma unroll
        for (int r = 0; r < 2; r++) {
            int lin = r * 256 + tid;
            int c = lin >> 7, od = lin & 127;
            float sum = s_part[(0 * G_ + c) * D_ + od] + s_part[(1 * G_ + c) * D_ + od]
                      + s_part[(2 * G_ + c) * D_ + od] + s_part[(3 * G_ + c) * D_ + od];
            s_q[c][od] = sum + bq_g[od];
        }
    }
    __syncthreads();

    // ---- Prefetch Wv slice (latency hidden behind C/D/E/F) ----
    float2 wv2[32];
    #pragma unroll
    for (int i = 0; i < 32; i++)
        wv2[i] = ((const float2*)(wv_g + (size_t)(js * 32 + i) * D_))[op];

    // ---- Phase C: t[c,h,j] = 0.25 * sum_d' q[c,h*16+d'] * Wk[j, h*16+d'] ----
    {
        int h = tid & 7, jb = tid >> 3;    // jb in 0..31, j = jb + jj*32
        float wk[4][16];
        #pragma unroll
        for (int jj = 0; jj < 4; jj++) {
            int j = jb + jj * 32;
            const float4* pk = (const float4*)(wk_g + j * D_ + h * 16);
            float4 k0 = pk[0], k1 = pk[1], k2 = pk[2], k3 = pk[3];
            wk[jj][0]  = k0.x; wk[jj][1]  = k0.y; wk[jj][2]  = k0.z; wk[jj][3]  = k0.w;
            wk[jj][4]  = k1.x; wk[jj][5]  = k1.y; wk[jj][6]  = k1.z; wk[jj][7]  = k1.w;
            wk[jj][8]  = k2.x; wk[jj][9]  = k2.y; wk[jj][10] = k2.z; wk[jj][11] = k2.w;
            wk[jj][12] = k3.x; wk[jj][13] = k3.y; wk[jj][14] = k3.z; wk[jj][15] = k3.w;
        }
        #pragma unroll
        for (int c = 0; c < G_; c++) {
            float qv[16];
            #pragma unroll
            for (int d = 0; d < 16; d++) qv[d] = s_q[c][h * 16 + d];
            #pragma unroll
            for (int jj = 0; jj < 4; jj++) {
                float acc = 0.f;
                #pragma unroll
                for (int d = 0; d < 16; d++) acc = fmaf(qv[d], wk[jj][d], acc);
                s_ts[(c * H_ + h) * 132 + jb + jj * 32] = acc * 0.25f;
            }
        }
    }
    __syncthreads();

    // ---- Phase D: energy[c,h,n] = sum_j an[c,n,j] * t[c,h,j], + mask bias ----
    {
        int c = tid >> 6, h = (tid >> 3) & 7, n0 = tid & 7;
        const float* trow = &s_ts[(c * H_ + h) * 132];
        float acc[4] = {0.f, 0.f, 0.f, 0.f};
        #pragma unroll
        for (int jc = 0; jc < 16; jc++) {
            float4 ta = *(const float4*)(trow + jc * 8);
            float4 tb = *(const float4*)(trow + jc * 8 + 4);
            #pragma unroll
            for (int r = 0; r < 4; r++) {
                int n = n0 + r * 8;
                uint4 av = *(const uint4*)(s_an + (c * N_ + n) * 136 + jc * 8);
                float s = acc[r];
                s = fmaf(bflo(av.x), ta.x, s);  s = fmaf(bfhi(av.x), ta.y, s);
                s = fmaf(bflo(av.y), ta.z, s);  s = fmaf(bfhi(av.y), ta.w, s);
                s = fmaf(bflo(av.z), tb.x, s);  s = fmaf(bfhi(av.z), tb.y, s);
                s = fmaf(bflo(av.w), tb.z, s);  s = fmaf(bfhi(av.w), tb.w, s);
                acc[r] = s;
            }
        }
        #pragma unroll
        for (int r = 0; r < 4; r++) {
            int n = n0 + r * 8;
            float mk = s_mask[c][n];
            s_eat[c][h][n] = acc[r] + (1.0f - mk) * (-1.0e9f);
        }
    }
    __syncthreads();

    // ---- Phase E: softmax over n per (c,h); attn, attnm, asum ----
    if (tid < G_ * H_) {
        int c = tid >> 3, h = tid & 7;
        float e[N_];
        float m = -3.0e38f;
        #pragma unroll
        for (int n = 0; n < N_; n++) { e[n] = s_eat[c][h][n]; m = fmaxf(m, e[n]); }
        float sum = 0.f;
        #pragma unroll
        for (int n = 0; n < N_; n++) { float p = __expf(e[n] - m); e[n] = p; sum += p; }
        float inv = 1.0f / sum;
        float asum = 0.f;
        #pragma unroll
        for (int n = 0; n < N_; n++) {
            float a  = e[n] * inv;
            float am = a * s_mask[c][n];
            s_ao[c][h][n]  = a;
            s_eat[c][h][n] = am;
            asum += am;
        }
        s_asum[c][h] = asum;
    }
    __syncthreads();

    // ---- Phase E2: write attn output (f32, [B,H,C,N]) ----
    {
        int ch = tid >> 3, i8 = tid & 7;
        int c = ch >> 3, h = ch & 7;
        float4 w;
        w.x = s_ao[c][h][i8 * 4];
        w.y = s_ao[c][h][i8 * 4 + 1];
        w.z = s_ao[c][h][i8 * 4 + 2];
        w.w = s_ao[c][h][i8 * 4 + 3];
        size_t off = ((size_t)(b * H_ + h) * C_ + (c0 + c)) * N_ + i8 * 4;
        *(float4*)(attn_o + off) = w;
    }

    // ---- Phase F: s[c,h,j] = sum_n attnm[c,h,n] * an[c,n,j] (overwrites s_ts) ----
    {
        int c = tid >> 6, h = (tid >> 3) & 7, jg = tid & 7;
        int j0 = jg * 16;
        float acc[16];
        #pragma unroll
        for (int i = 0; i < 16; i++) acc[i] = 0.f;
        #pragma unroll 4
        for (int n = 0; n < N_; n++) {
            float am = s_eat[c][h][n];
            const u16* arow = s_an + (c * N_ + n) * 136 + j0;
            uint4 v0 = *(const uint4*)(arow);
            uint4 v1 = *(const uint4*)(arow + 8);
            acc[0]  = fmaf(am, bflo(v0.x), acc[0]);   acc[1]  = fmaf(am, bfhi(v0.x), acc[1]);
            acc[2]  = fmaf(am, bflo(v0.y), acc[2]);   acc[3]  = fmaf(am, bfhi(v0.y), acc[3]);
            acc[4]  = fmaf(am, bflo(v0.z), acc[4]);   acc[5]  = fmaf(am, bfhi(v0.z), acc[5]);
            acc[6]  = fmaf(am, bflo(v0.w), acc[6]);   acc[7]  = fmaf(am, bfhi(v0.w), acc[7]);
            acc[8]  = fmaf(am, bflo(v1.x), acc[8]);   acc[9]  = fmaf(am, bfhi(v1.x), acc[9]);
            acc[10] = fmaf(am, bflo(v1.y), acc[10]);  acc[11] = fmaf(am, bfhi(v1.y), acc[11]);
            acc[12] = fmaf(am, bflo(v1.z), acc[12]);  acc[13] = fmaf(am, bfhi(v1.z), acc[13]);
            acc[14] = fmaf(am, bflo(v1.w), acc[14]);  acc[15] = fmaf(am, bfhi(v1.w), acc[15]);
        }
        float* srow = &s_ts[(c * H_ + h) * 132 + j0];
        *(float4*)(srow)      = make_float4(acc[0], acc[1], acc[2], acc[3]);
        *(float4*)(srow + 4)  = make_float4(acc[4], acc[5], acc[6], acc[7]);
        *(float4*)(srow + 8)  = make_float4(acc[8], acc[9], acc[10], acc[11]);
        *(float4*)(srow + 12) = make_float4(acc[12], acc[13], acc[14], acc[15]);
    }
    __syncthreads();

    // ---- Phase G: ctx partials — thread (op,js), Wv read once per block ----
    {
        int h = op >> 3;                  // od = 2*op -> head = od/16
        float acc0[G_], acc1[G_];
        #pragma unroll
        for (int c = 0; c < G_; c++) { acc0[c] = 0.f; acc1[c] = 0.f; }
        #pragma unroll
        for (int i4 = 0; i4 < 8; i4++) {
            #pragma unroll
            for (int c = 0; c < G_; c++) {
                float4 s4 = *(const float4*)&s_ts[(c * H_ + h) * 132 + js * 32 + i4 * 4];
                float2 w0 = wv2[i4 * 4], w1 = wv2[i4 * 4 + 1];
                float2 w2 = wv2[i4 * 4 + 2], w3 = wv2[i4 * 4 + 3];
                acc0[c] = fmaf(s4.x, w0.x, acc0[c]); acc1[c] = fmaf(s4.x, w0.y, acc1[c]);
                acc0[c] = fmaf(s4.y, w1.x, acc0[c]); acc1[c] = fmaf(s4.y, w1.y, acc1[c]);
                acc0[c] = fmaf(s4.z, w2.x, acc0[c]); acc1[c] = fmaf(s4.z, w2.y, acc1[c]);
                acc0[c] = fmaf(s4.w, w3.x, acc0[c]); acc1[c] = fmaf(s4.w, w3.y, acc1[c]);
            }
        }
        // wait: for head h, only j in [h*16, h*16+16) contributes?  NO —
        // s (length 128) contracts fully against Wv rows; srow is s[c,h,:],
        // the per-head attention-weighted sum over all 128 j. Full j-range
        // is correct (matches round-2 phase G).
        float* s_gp = (float*)s_an;       // 8 KB scratch, s_an dead after F
        #pragma unroll
        for (int c = 0; c < G_; c++) {
            *(float2*)&s_gp[(js * G_ + c) * D_ + 2 * op] = make_float2(acc0[c], acc1[c]);
        }
    }
    __syncthreads();

    // ---- Phase G2: reduce partials + bias + residual -> ctx ----
    {
        const float* s_gp = (const float*)s_an;
        #pragma unroll
        for (int r = 0; r < 2; r++) {
            int lin = r * 256 + tid;
            int c = lin >> 7, od = lin & 127;
            int h = od >> 4;
            float sum = s_gp[(0 * G_ + c) * D_ + od] + s_gp[(1 * G_ + c) * D_ + od]
                      + s_gp[(2 * G_ + c) * D_ + od] + s_gp[(3 * G_ + c) * D_ + od];
            float r0 = sum + s_asum[c][h] * bv_g[od] + s_q[c][od];
            ctx_o[((size_t)(b * C_ + c0 + c)) * D_ + od] = r0;
        }
    }
}

extern "C" void kernel_launch(void* const* d_in, const int* in_sizes, int n_in,
                              void* d_out, int out_size, void* d_ws, size_t ws_size,
                              hipStream_t stream) {
    const float* aq   = (const float*)d_in[0];
    const float* an   = (const float*)d_in[1];
    const float* dist = (const float*)d_in[2];
    const float* mask = (const float*)d_in[3];
    const float* wq   = (const float*)d_in[4];
    const float* bq   = (const float*)d_in[5];
    const float* wk   = (const float*)d_in[6];
    // d_in[7] = bk: adds a per-(c,h) constant over n -> cancels exactly in softmax.
    const float* wv   = (const float*)d_in[8];
    const float* bv   = (const float*)d_in[9];
    const float* wf   = (const float*)d_in[10];
    const float* bfb  = (const float*)d_in[11];

    float* attn_o = (float*)d_out;
    float* ctx_o  = attn_o + (size_t)B_ * H_ * C_ * N_;

    dim3 grid(B_ * C_ / G_), block(T_);
    hipLaunchKernelGGL(la_kernel, grid, block, 0, stream,
                       aq, an, dist, mask, wq, bq, wk, wv, bv, wf, bfb,
                       attn_o, ctx_o);
}

// Round 5
// 437.110 us; speedup vs baseline: 1.2327x; 1.0568x over previous
//
#include <hip/hip_runtime.h>
#include <hip/hip_fp16.h>
#include <cstdint>

// LocalAttention fused kernel, round 5: packed-f16 inner math (round-4 design
// with builtin-type fixes: __builtin_amdgcn_cvt_pkrtz / _fdot2 use __fp16
// ext-vectors on this ROCm; interop via __builtin_bit_cast; packed FMA via
// HIP __half2/__hfma2).
//
// vs round 3 (190us, VALUBusy 53%, VALU-issue-limited ~100 busy-us):
//  - an/t cached in LDS as f16 pairs (v_cvt_pkrtz packs 2 vals in 1 inst;
//    f16 also 8x more accurate than the old bf16 cache)
//  - Phase D energy contraction via v_dot2_f32_f16 (2 MACs/inst, fp32 acc)
//  - Phase F s-contraction via v_pk_fma_f16 (2 MACs/inst, f16x2 acc)
//  - attn written directly from softmax phase (s_ao removed)
// VALU inst count ~4000 -> ~2400 per thread; predict ~125us.
//
// Algebra (exact in real arithmetic):
//   energy[h,n] = sum_j an[n,j] * t[h,j],  t[h,j] = 0.25 * sum_d' q[h,d'] Wk[j,h*16+d']
//     (bk constant over n -> cancels in softmax)
//   ctx[h,d'] = sum_j s[h,j] * Wv[j,h*16+d'] + (sum_n attnm[h,n]) * bv[h,d']
//     with s[h,:] = attnm[h,:] @ an

#define B_ 16
#define C_ 1024
#define N_ 32
#define H_ 8
#define D_ 128
#define G_ 4
#define T_ 256

typedef unsigned short u16;
typedef unsigned int u32;
typedef __fp16 hw2 __attribute__((ext_vector_type(2)));   // matches builtin sigs

__device__ __forceinline__ u32 pkrtz(float a, float b) {
    hw2 r = __builtin_amdgcn_cvt_pkrtz(a, b);
    return __builtin_bit_cast(u32, r);
}
__device__ __forceinline__ float fdot2(u32 a, u32 b, float c) {
#if __has_builtin(__builtin_amdgcn_fdot2)
    return __builtin_amdgcn_fdot2(__builtin_bit_cast(hw2, a),
                                  __builtin_bit_cast(hw2, b), c, false);
#else
    float2 A = __half22float2(__builtin_bit_cast(__half2, a));
    float2 B = __half22float2(__builtin_bit_cast(__half2, b));
    return fmaf(A.y, B.y, fmaf(A.x, B.x, c));
#endif
}
__device__ __forceinline__ __half2 fma2(u32 a, u32 b, __half2 c) {
    return __hfma2(__builtin_bit_cast(__half2, a),
                   __builtin_bit_cast(__half2, b), c);
}
__device__ __forceinline__ float swishf(float x) {
    float s = __builtin_amdgcn_rcpf(1.0f + __expf(-x));
    return x * s;
}

__global__ __launch_bounds__(T_, 2)
void la_kernel(const float* __restrict__ aq_g,  const float* __restrict__ an_g,
               const float* __restrict__ dist_g, const float* __restrict__ mask_g,
               const float* __restrict__ wq_g,  const float* __restrict__ bq_g,
               const float* __restrict__ wk_g,
               const float* __restrict__ wv_g,  const float* __restrict__ bv_g,
               const float* __restrict__ wf_g,  const float* __restrict__ bfb_g,
               float* __restrict__ attn_o, float* __restrict__ ctx_o)
{
    // LDS: 34816(s_an) + 16896(s_ts) + 2048 + 2048 + 4224 + 512+512+128+512+512 = 62208 B
    __shared__ __align__(16) u16   s_an[G_ * N_ * 136];   // gated neighbors f16; f32 scratch for G-partials after F
    __shared__ __align__(16) float s_ts[G_ * H_ * 132];   // B-partials(f32) -> t(f16 pairs, u32 view) -> s(f32)
    __shared__ float s_q[G_][D_];                         // projected query (unscaled)
    __shared__ float s_aq[G_][D_];                        // raw atom_query
    __shared__ __align__(8) float s_eat[G_][H_][33];      // energy f32 (D/E); then (am,am) f16 pairs u32 view (F)
    __shared__ float s_dist[G_][N_];
    __shared__ float s_mask[G_][N_];
    __shared__ float s_asum[G_][H_];
    __shared__ __align__(16) float s_wf[D_];
    __shared__ __align__(16) float s_bfb[D_];

    const int tid = threadIdx.x;
    const int b   = blockIdx.x >> 8;          // 256 c-groups per b
    const int c0  = (blockIdx.x & 255) << 2;  // G_=4 c's per block

    const int op = tid & 63;                  // output-pair index (od = 2*op)
    const int js = tid >> 6;                  // j-slice index (rows js*32 .. js*32+31)

    // ---- Prefetch Wq slice into registers (overlaps Phase A an-stream) ----
    float2 wq2[32];
    #pragma unroll
    for (int i = 0; i < 32; i++)
        wq2[i] = ((const float2*)(wq_g + (size_t)(js * 32 + i) * D_))[op];

    // ---- Phase 0: stage small tensors ----
    if (tid < D_) {
        s_wf[tid]  = wf_g[tid];
        s_bfb[tid] = bfb_g[tid];
        int c = tid >> 5, n = tid & 31;
        int gi = (b * C_ + c0 + c) * N_ + n;
        s_dist[c][n] = dist_g[gi];
        s_mask[c][n] = mask_g[gi];
    }
    {
        int c = tid >> 7, d = tid & 127;
        s_aq[c][d] = aq_g[(b * C_ + c0 + c) * D_ + d];
        int i2 = tid + 256;
        c = i2 >> 7; d = i2 & 127;
        s_aq[c][d] = aq_g[(b * C_ + c0 + c) * D_ + d];
    }
    __syncthreads();

    // ---- Phase A: stream + swish-gate atom_neighbor -> s_an (f16 pairs) ----
    {
        const float4* gan = (const float4*)(an_g + (size_t)(b * C_ + c0) * N_ * D_);
        #pragma unroll
        for (int k = 0; k < 16; k++) {
            int ci = k * T_ + tid;                  // float4 chunk index, 4096 total
            float4 v = gan[ci];
            int d4 = ci & 31, n = (ci >> 5) & 31, c = ci >> 10;
            float dist = s_dist[c][n];
            int d0 = d4 << 2;
            float4 wf = *(const float4*)&s_wf[d0];
            float4 bb = *(const float4*)&s_bfb[d0];
            float g0 = swishf(fmaf(dist, wf.x, bb.x));
            float g1 = swishf(fmaf(dist, wf.y, bb.y));
            float g2 = swishf(fmaf(dist, wf.z, bb.z));
            float g3 = swishf(fmaf(dist, wf.w, bb.w));
            u32 o0 = pkrtz(v.x * g0, v.y * g1);
            u32 o1 = pkrtz(v.z * g2, v.w * g3);
            *(uint2*)(s_an + (c * N_ + n) * 136 + d0) = make_uint2(o0, o1);
        }
    }

    // ---- Phase B: q partials — thread (op,js) covers j in [js*32, js*32+32) ----
    {
        float acc0[G_], acc1[G_];
        #pragma unroll
        for (int c = 0; c < G_; c++) { acc0[c] = 0.f; acc1[c] = 0.f; }
        #pragma unroll
        for (int i4 = 0; i4 < 8; i4++) {
            #pragma unroll
            for (int c = 0; c < G_; c++) {
                float4 a4 = *(const float4*)&s_aq[c][js * 32 + i4 * 4];
                float2 w0 = wq2[i4 * 4], w1 = wq2[i4 * 4 + 1];
                float2 w2 = wq2[i4 * 4 + 2], w3 = wq2[i4 * 4 + 3];
                acc0[c] = fmaf(a4.x, w0.x, acc0[c]); acc1[c] = fmaf(a4.x, w0.y, acc1[c]);
                acc0[c] = fmaf(a4.y, w1.x, acc0[c]); acc1[c] = fmaf(a4.y, w1.y, acc1[c]);
                acc0[c] = fmaf(a4.z, w2.x, acc0[c]); acc1[c] = fmaf(a4.z, w2.y, acc1[c]);
                acc0[c] = fmaf(a4.w, w3.x, acc0[c]); acc1[c] = fmaf(a4.w, w3.y, acc1[c]);
            }
        }
        float* s_part = s_ts;   // [js][c][128] scratch, 8 KB
        #pragma unroll
        for (int c = 0; c < G_; c++) {
            *(float2*)&s_part[(js * G_ + c) * D_ + 2 * op] = make_float2(acc0[c], acc1[c]);
        }
    }
    __syncthreads();

    // ---- Phase B2: reduce partials -> s_q ----
    {
        const float* s_part = s_ts;
        #pragma unroll
        for (int r = 0; r < 2; r++) {
            int lin = r * 256 + tid;
            int c = lin >> 7, od = lin & 127;
            float sum = s_part[(0 * G_ + c) * D_ + od] + s_part[(1 * G_ + c) * D_ + od]
                      + s_part[(2 * G_ + c) * D_ + od] + s_part[(3 * G_ + c) * D_ + od];
            s_q[c][od] = sum + bq_g[od];
        }
    }
    __syncthreads();

    // ---- Prefetch Wv slice (latency hidden behind C/D/E/F) ----
    float2 wv2[32];
    #pragma unroll
    for (int i = 0; i < 32; i++)
        wv2[i] = ((const float2*)(wv_g + (size_t)(js * 32 + i) * D_))[op];

    // ---- Phase C: t[c,h,j] = 0.25*sum_d' q*Wk, packed f16 pairs into t32 ----
    // thread (h, jb) owns j in {2jb, 2jb+1, 64+2jb, 64+2jb+1}
    {
        u32* t32 = (u32*)s_ts;             // [c*8+h][68] u32 (f16 pairs), 8.7 KB
        int h = tid & 7, jb = tid >> 3;    // jb in 0..31
        float wk[4][16];
        #pragma unroll
        for (int jj = 0; jj < 4; jj++) {
            int j = 2 * jb + (jj & 1) + (jj >> 1) * 64;
            const float4* pk = (const float4*)(wk_g + j * D_ + h * 16);
            float4 k0 = pk[0], k1 = pk[1], k2 = pk[2], k3 = pk[3];
            wk[jj][0]  = k0.x; wk[jj][1]  = k0.y; wk[jj][2]  = k0.z; wk[jj][3]  = k0.w;
            wk[jj][4]  = k1.x; wk[jj][5]  = k1.y; wk[jj][6]  = k1.z; wk[jj][7]  = k1.w;
            wk[jj][8]  = k2.x; wk[jj][9]  = k2.y; wk[jj][10] = k2.z; wk[jj][11] = k2.w;
            wk[jj][12] = k3.x; wk[jj][13] = k3.y; wk[jj][14] = k3.z; wk[jj][15] = k3.w;
        }
        #pragma unroll
        for (int c = 0; c < G_; c++) {
            float qv[16];
            #pragma unroll
            for (int d = 0; d < 16; d++) qv[d] = s_q[c][h * 16 + d];
            float acc[4];
            #pragma unroll
            for (int jj = 0; jj < 4; jj++) {
                float a = 0.f;
                #pragma unroll
                for (int d = 0; d < 16; d++) a = fmaf(qv[d], wk[jj][d], a);
                acc[jj] = a * 0.25f;
            }
            t32[(c * 8 + h) * 68 + jb]      = pkrtz(acc[0], acc[1]);  // pair jb    (j=2jb,2jb+1)
            t32[(c * 8 + h) * 68 + 32 + jb] = pkrtz(acc[2], acc[3]);  // pair jb+32 (j=64+2jb,..)
        }
    }
    __syncthreads();

    // ---- Phase D: energy via v_dot2_f32_f16, fp32 accumulate ----
    {
        const u32* t32 = (const u32*)s_ts;
        int c = tid >> 6, h = (tid >> 3) & 7, n0 = tid & 7;
        const uint4* trow = (const uint4*)(t32 + (c * 8 + h) * 68);
        float acc[4] = {0.f, 0.f, 0.f, 0.f};
        #pragma unroll
        for (int jc = 0; jc < 16; jc++) {
            uint4 t4 = trow[jc];               // 8 f16 = j 8jc..8jc+7
            #pragma unroll
            for (int r = 0; r < 4; r++) {
                int n = n0 + r * 8;
                uint4 a4 = *(const uint4*)(s_an + (c * N_ + n) * 136 + jc * 8);
                float s = acc[r];
                s = fdot2(a4.x, t4.x, s);
                s = fdot2(a4.y, t4.y, s);
                s = fdot2(a4.z, t4.z, s);
                s = fdot2(a4.w, t4.w, s);
                acc[r] = s;
            }
        }
        #pragma unroll
        for (int r = 0; r < 4; r++) {
            int n = n0 + r * 8;
            float mk = s_mask[c][n];
            s_eat[c][h][n] = acc[r] + (1.0f - mk) * (-1.0e9f);
        }
    }
    __syncthreads();

    // ---- Phase E: softmax; write attn to global; store (am,am) f16 pairs ----
    if (tid < G_ * H_) {
        int c = tid >> 3, h = tid & 7;
        float e[N_];
        float m = -3.0e38f;
        #pragma unroll
        for (int n = 0; n < N_; n++) { e[n] = s_eat[c][h][n]; m = fmaxf(m, e[n]); }
        float sum = 0.f;
        #pragma unroll
        for (int n = 0; n < N_; n++) { float p = __expf(e[n] - m); e[n] = p; sum += p; }
        float inv = 1.0f / sum;
        u32* ampk = (u32*)&s_eat[c][h][0];
        float asum = 0.f;
        size_t off = ((size_t)(b * H_ + h) * C_ + (c0 + c)) * N_;
        #pragma unroll
        for (int n4 = 0; n4 < 8; n4++) {
            float4 w;
            w.x = e[n4 * 4]     * inv;
            w.y = e[n4 * 4 + 1] * inv;
            w.z = e[n4 * 4 + 2] * inv;
            w.w = e[n4 * 4 + 3] * inv;
            *(float4*)(attn_o + off + n4 * 4) = w;
            float am0 = w.x * s_mask[c][n4 * 4];
            float am1 = w.y * s_mask[c][n4 * 4 + 1];
            float am2 = w.z * s_mask[c][n4 * 4 + 2];
            float am3 = w.w * s_mask[c][n4 * 4 + 3];
            asum += am0 + am1 + am2 + am3;
            ampk[n4 * 4]     = pkrtz(am0, am0);
            ampk[n4 * 4 + 1] = pkrtz(am1, am1);
            ampk[n4 * 4 + 2] = pkrtz(am2, am2);
            ampk[n4 * 4 + 3] = pkrtz(am3, am3);
        }
        s_asum[c][h] = asum;
    }
    __syncthreads();

    // ---- Phase F: s[c,h,j] = sum_n am*an via v_pk_fma_f16 (f16x2 acc) ----
    {
        int c = tid >> 6, h = (tid >> 3) & 7, jg = tid & 7;
        const u32* ampk = (const u32*)&s_eat[c][h][0];
        __half2 acc2[8];
        #pragma unroll
        for (int i = 0; i < 8; i++) acc2[i] = __float2half2_rn(0.f);
        #pragma unroll 4
        for (int n = 0; n < N_; n++) {
            u32 am2 = ampk[n];
            const uint4* arow = (const uint4*)(s_an + (c * N_ + n) * 136 + jg * 16);
            uint4 a0 = arow[0], a1 = arow[1];
            acc2[0] = fma2(a0.x, am2, acc2[0]);
            acc2[1] = fma2(a0.y, am2, acc2[1]);
            acc2[2] = fma2(a0.z, am2, acc2[2]);
            acc2[3] = fma2(a0.w, am2, acc2[3]);
            acc2[4] = fma2(a1.x, am2, acc2[4]);
            acc2[5] = fma2(a1.y, am2, acc2[5]);
            acc2[6] = fma2(a1.z, am2, acc2[6]);
            acc2[7] = fma2(a1.w, am2, acc2[7]);
        }
        float* srow = &s_ts[(c * H_ + h) * 132 + jg * 16];
        #pragma unroll
        for (int p = 0; p < 4; p++) {
            float2 lo = __half22float2(acc2[p * 2]);
            float2 hi = __half22float2(acc2[p * 2 + 1]);
            *(float4*)(srow + p * 4) = make_float4(lo.x, lo.y, hi.x, hi.y);
        }
    }
    __syncthreads();

    // ---- Phase G: ctx partials — thread (op,js), Wv read once per block ----
    {
        int h = op >> 3;                  // od = 2*op -> head = od/16
        float acc0[G_], acc1[G_];
        #pragma unroll
        for (int c = 0; c < G_; c++) { acc0[c] = 0.f; acc1[c] = 0.f; }
        #pragma unroll
        for (int i4 = 0; i4 < 8; i4++) {
            #pragma unroll
            for (int c = 0; c < G_; c++) {
                float4 s4 = *(const float4*)&s_ts[(c * H_ + h) * 132 + js * 32 + i4 * 4];
                float2 w0 = wv2[i4 * 4], w1 = wv2[i4 * 4 + 1];
                float2 w2 = wv2[i4 * 4 + 2], w3 = wv2[i4 * 4 + 3];
                acc0[c] = fmaf(s4.x, w0.x, acc0[c]); acc1[c] = fmaf(s4.x, w0.y, acc1[c]);
                acc0[c] = fmaf(s4.y, w1.x, acc0[c]); acc1[c] = fmaf(s4.y, w1.y, acc1[c]);
                acc0[c] = fmaf(s4.z, w2.x, acc0[c]); acc1[c] = fmaf(s4.z, w2.y, acc1[c]);
                acc0[c] = fmaf(s4.w, w3.x, acc0[c]); acc1[c] = fmaf(s4.w, w3.y, acc1[c]);
            }
        }
        float* s_gp = (float*)s_an;       // 8 KB scratch, s_an dead after F
        #pragma unroll
        for (int c = 0; c < G_; c++) {
            *(float2*)&s_gp[(js * G_ + c) * D_ + 2 * op] = make_float2(acc0[c], acc1[c]);
        }
    }
    __syncthreads();

    // ---- Phase G2: reduce partials + bias + residual -> ctx ----
    {
        const float* s_gp = (const float*)s_an;
        #pragma unroll
        for (int r = 0; r < 2; r++) {
            int lin = r * 256 + tid;
            int c = lin >> 7, od = lin & 127;
            int h = od >> 4;
            float sum = s_gp[(0 * G_ + c) * D_ + od] + s_gp[(1 * G_ + c) * D_ + od]
                      + s_gp[(2 * G_ + c) * D_ + od] + s_gp[(3 * G_ + c) * D_ + od];
            float r0 = sum + s_asum[c][h] * bv_g[od] + s_q[c][od];
            ctx_o[((size_t)(b * C_ + c0 + c)) * D_ + od] = r0;
        }
    }
}

extern "C" void kernel_launch(void* const* d_in, const int* in_sizes, int n_in,
                              void* d_out, int out_size, void* d_ws, size_t ws_size,
                              hipStream_t stream) {
    const float* aq   = (const float*)d_in[0];
    const float* an   = (const float*)d_in[1];
    const float* dist = (const float*)d_in[2];
    const float* mask = (const float*)d_in[3];
    const float* wq   = (const float*)d_in[4];
    const float* bq   = (const float*)d_in[5];
    const float* wk   = (const float*)d_in[6];
    // d_in[7] = bk: constant over n -> cancels exactly in softmax.
    const float* wv   = (const float*)d_in[8];
    const float* bv   = (const float*)d_in[9];
    const float* wf   = (const float*)d_in[10];
    const float* bfb  = (const float*)d_in[11];

    float* attn_o = (float*)d_out;
    float* ctx_o  = attn_o + (size_t)B_ * H_ * C_ * N_;

    dim3 grid(B_ * C_ / G_), block(T_);
    hipLaunchKernelGGL(la_kernel, grid, block, 0, stream,
                       aq, an, dist, mask, wq, bq, wk, wv, bv, wf, bfb,
                       attn_o, ctx_o);
}